// Round 14
// baseline (87.897 us; speedup 1.0000x reference)
//
#include <hip/hip_runtime.h>

// Shapes (fixed): T=8, S=512, B=8, D=512, H=8, hd=64, BH=64, NE=32, NI=64.
// out: (64, 512, 512) f32.
//
// Math reduction: sum_p telescopes to (sum_t Q_t)(sum_t K_t)^T * scale, so
//   p = (Xsum@Wq^T + 8 bq)(Xsum@Wk^T + 8 bk)^T / 64   (per bh batch, hd=64)
// The 1/64 is folded into Q at projection time.
//
// Q/K are stored in MFMA-FRAGMENT ORDER: [bh][blk16][half][lane][16B], so
// k_attn operand loads are fully-coalesced 1KB dwordx4 reads.
//
// exp-MLP epilogue: 2048-bucket chord LUT in INDEX SPACE (a',b' float2,
// 16KB LDS): xu = a'*u + b', u = (tp-LO)*INVW; exact PWL eval off knot
// buckets, exact at clamp ends.
//
// R13->R14: ONE variable - block granularity. 512 blocks x 512 thr x 64 rows
// (was 2048 x 256 x 16): single co-resident generation (2 blocks/CU), LUT
// stages /4, fac tails /4, retire drains /4. Per-wave shape unchanged-proven:
// 16r x 256c acc[16] = R2's no-spill config (60 VGPR + 64 AGPR = 124 <= 128).
//
// REGISTER RULE (R4/R6/R8): VGPR+AGPR one budget. Budget 128 = (512,4).
// Spill tripwire in counters: WRITE >> 90MB or FETCH >> 15MB.

#define T_  8
#define NE_ 32
#define NI_ 64

#define LUT_N   2048
#define LUT_LO  -20.0f
#define LUT_HI  3.0f
#define LUT_INVW (LUT_N / (LUT_HI - LUT_LO))     // 2048/23
#define LUT_W    ((LUT_HI - LUT_LO) / LUT_N)

typedef __attribute__((ext_vector_type(8))) short bf16x8;
typedef __attribute__((ext_vector_type(4))) float f32x4;
typedef __attribute__((ext_vector_type(4))) unsigned int u32x4;

// workspace layout, in ushort elements
#define XS_OFF 0u        // Xsum bf16 (4096 x 512)
#define WQ_OFF 2097152u  // Wq bf16 (512 x 512)
#define WK_OFF 2359296u  // Wk bf16
#define QB_OFF 2621440u  // Q bf16 frag-order (64*32*2*1024B), pre-scaled 1/64
#define KB_OFF 4718592u  // K bf16 frag-order
#define LUT_OFF 6815744u // float2 lut[2048] = 16 KB (index-space chord a',b')

__device__ inline unsigned short f2bf(float f) {
  union { float f; unsigned u; } v; v.f = f;
  unsigned r = v.u + 0x7FFFu + ((v.u >> 16) & 1u);
  return (unsigned short)(r >> 16);
}

__device__ inline void gload16(const void* g, void* l) {
  __builtin_amdgcn_global_load_lds(
      (const __attribute__((address_space(1))) void*)g,
      (__attribute__((address_space(3))) void*)l, 16, 0, 0);
}

// XOR-swizzled LDS read (k_proj GEMM tiles): 128B rows, slot ^ (row&7)
__device__ inline bf16x8 lds_read_swz(const unsigned short* base, int row, int byteoff) {
  int addr = row * 128 + (byteoff ^ ((row & 7) << 4));
  return *(const bf16x8*)((const char*)base + addr);
}

// inv-MLP with 4-way ILP accumulators (64-deep chain -> 16-deep)
__device__ inline float invmlp4(float x, const float* __restrict__ w1,
                                const float* __restrict__ b1,
                                const float* __restrict__ w2, float b2) {
  float a0 = b2, a1 = 0.f, a2 = 0.f, a3 = 0.f;
#pragma unroll
  for (int n = 0; n < NI_; n += 4) {
    a0 += w2[n + 0] * fmaxf(x * w1[n + 0] + b1[n + 0], 0.0f);
    a1 += w2[n + 1] * fmaxf(x * w1[n + 1] + b1[n + 1], 0.0f);
    a2 += w2[n + 2] * fmaxf(x * w1[n + 2] + b1[n + 2], 0.0f);
    a3 += w2[n + 3] * fmaxf(x * w1[n + 3] + b1[n + 3], 0.0f);
  }
  return (a0 + a1) + (a2 + a3);
}

__device__ inline float expmlp_exact(float t, const float* __restrict__ w1,
                                     const float* __restrict__ b1,
                                     const float* __restrict__ w2, float b2) {
  float a = b2;
#pragma unroll
  for (int n = 0; n < NE_; n++) a += w2[n] * fmaxf(t * w1[n] + b1[n], 0.0f);
  return a;
}

// ---------------------------------------------------------------------------
// Kernel 1: Xsum = sum_t sx[t] (f32->bf16, nt loads), Wq/Wk casts, chord LUT.
__global__ __launch_bounds__(256) void k_pre(
    const float* __restrict__ sx, const float* __restrict__ wq,
    const float* __restrict__ wk, const float* __restrict__ ew1,
    const float* __restrict__ eb1, const float* __restrict__ ew2,
    const float* __restrict__ eb2p,
    unsigned short* __restrict__ xs, unsigned short* __restrict__ wqb,
    unsigned short* __restrict__ wkb, float2* __restrict__ lut) {
  int bx = blockIdx.x, tid = threadIdx.x;
  if (bx < 2048) {
    size_t i = ((size_t)bx * 256 + tid) * 4;
    f32x4 a = __builtin_nontemporal_load((const f32x4*)(sx + i));
#pragma unroll
    for (int t = 1; t < T_; t++) {
      f32x4 v = __builtin_nontemporal_load((const f32x4*)(sx + (size_t)t * 2097152 + i));
      a += v;
    }
    ushort4 o; o.x = f2bf(a[0]); o.y = f2bf(a[1]); o.z = f2bf(a[2]); o.w = f2bf(a[3]);
    *(ushort4*)(xs + i) = o;
  } else if (bx < 2560) {
    const float* src = (bx < 2304) ? wq : wk;
    unsigned short* dst = (bx < 2304) ? wqb : wkb;
    int base = (bx < 2304) ? 2048 : 2304;
    size_t i = ((size_t)(bx - base) * 256 + tid) * 4;
    float4 a = *(const float4*)(src + i);
    ushort4 o; o.x = f2bf(a.x); o.y = f2bf(a.y); o.z = f2bf(a.z); o.w = f2bf(a.w);
    *(ushort4*)(dst + i) = o;
  } else {
    // index-space chord LUT: xu(u) = a'*u + b' on bucket i (u in [i, i+1]);
    // a' = f(t_{i+1})-f(t_i), b' = f(t_i) - a'*i. Edges shared -> continuity.
    int i = (bx - 2560) * 256 + tid;
    if (i < LUT_N) {
      float b2 = eb2p[0];
      float tl = fmaf((float)i, LUT_W, LUT_LO);
      float th = fmaf((float)(i + 1), LUT_W, LUT_LO);
      float el = expmlp_exact(tl, ew1, eb1, ew2, b2);
      float eh = expmlp_exact(th, ew1, eb1, ew2, b2);
      float ap = eh - el;
      float bp = fmaf(-ap, (float)i, el);
      lut[i] = make_float2(ap, bp);
    }
  }
}

// ---------------------------------------------------------------------------
// Kernel 2: Y = Xsum(4096x512) @ W^T + 8*bias -> bf16 frag-order layout.
// z=0 (Q) additionally scaled by 1/64.  grid (64,4,2) = 512 blocks
// (2 blocks/CU), 256 thr, 64x128 tile: 4 waves of 32x64. LDS 24KB.
// Output restaged via LDS (reuses Bs) -> coalesced 16B stores.
__global__ __launch_bounds__(256, 2) void k_proj(
    const unsigned short* __restrict__ xs, const unsigned short* __restrict__ wb,
    const float* __restrict__ bq, const float* __restrict__ bk,
    unsigned short* __restrict__ outb) {
  __shared__ unsigned short As[64 * 64];    // 8 KB
  __shared__ unsigned short Bs[128 * 64];   // 16 KB (reused as Os)
  int tid = threadIdx.x;
  int lane = tid & 63, w = tid >> 6;
  int r0 = blockIdx.x * 64;                 // bx in [0,64)
  int c0 = blockIdx.y * 128;                // by in [0,4)
  int z = blockIdx.z;
  const unsigned short* W = wb + (size_t)z * 262144;
  const float* bias = z ? bk : bq;
  unsigned short* dst = outb + (size_t)z * 2097152;
  float sc = z ? 1.0f : (1.0f / 64.0f);

  int rgrp = lane >> 4, cl = lane & 15;
  int r0w = (w >> 1) * 32, c0w = (w & 1) * 64;

  f32x4 acc[2][4];
  f32x4 zero = {0.f, 0.f, 0.f, 0.f};
#pragma unroll
  for (int m = 0; m < 2; m++)
#pragma unroll
    for (int n = 0; n < 4; n++) acc[m][n] = zero;

  int rl = lane >> 3, slot = lane & 7;

  for (int kt = 0; kt < 8; kt++) {
    int k0 = kt * 64;
#pragma unroll
    for (int i = 0; i < 2; i++) {
      int chunk = w * 2 + i;
      int r = chunk * 8 + rl;
      int sw = (slot ^ (r & 7)) * 8;
      gload16(xs + (size_t)(r0 + r) * 512 + k0 + sw, (char*)As + chunk * 1024);
    }
#pragma unroll
    for (int i = 0; i < 4; i++) {
      int chunk = w * 4 + i;
      int r = chunk * 8 + rl;
      int sw = (slot ^ (r & 7)) * 8;
      gload16(W + (size_t)(c0 + r) * 512 + k0 + sw, (char*)Bs + chunk * 1024);
    }
    __syncthreads();
#pragma unroll
    for (int kb = 0; kb < 2; kb++) {
      bf16x8 af[2], bfr[4];
#pragma unroll
      for (int m = 0; m < 2; m++) af[m] = lds_read_swz(As, r0w + 16 * m + cl, kb * 64 + rgrp * 16);
#pragma unroll
      for (int n = 0; n < 4; n++) bfr[n] = lds_read_swz(Bs, c0w + 16 * n + cl, kb * 64 + rgrp * 16);
#pragma unroll
      for (int m = 0; m < 2; m++)
#pragma unroll
        for (int n = 0; n < 4; n++)
          acc[m][n] = __builtin_amdgcn_mfma_f32_16x16x32_bf16(af[m], bfr[n], acc[m][n], 0, 0, 0);
    }
    __syncthreads();
  }

  // stage: +8*bias, scale, cast -> Os (=Bs) in frag-order
  unsigned short* Os = Bs;
#pragma unroll
  for (int n = 0; n < 4; n++) {
    int cgl = c0w + 16 * n + cl;               // [0,128)
    float bv = 8.0f * bias[c0 + cgl];
    int hl = cgl >> 6, dh = cgl & 63;
    int hh = dh >> 5, rg2 = (dh >> 3) & 3, jj = dh & 7;
#pragma unroll
    for (int m = 0; m < 2; m++) {
#pragma unroll
      for (int j = 0; j < 4; j++) {
        int rgl = r0w + 16 * m + rgrp * 4 + j;  // [0,64)
        int b = rgl & 7, clsl = rgl >> 3;       // [0,8)
        Os[((((b * 2 + hl) * 2 + hh) * 4 + rg2) * 8 + clsl) * 8 + jj] =
            f2bf((acc[m][n][j] + bv) * sc);
      }
    }
  }
  __syncthreads();

  // coalesced store: 1024 x 16B units
  int cb = blockIdx.x >> 1;
  int clsbase = (blockIdx.x & 1) * 8;
  int h0 = c0 >> 6;
#pragma unroll
  for (int i2 = 0; i2 < 4; i2++) {
    int unit = i2 * 256 + tid;                  // [b:3][hl:1][hh:1][rg2:2][clsl:3]
    int clsl = unit & 7, rg2 = (unit >> 3) & 3, hh = (unit >> 5) & 1;
    int hl = (unit >> 6) & 1, b = unit >> 7;
    int bh = b * 8 + h0 + hl;
    size_t du = ((size_t)((bh * 32 + cb) * 2 + hh)) * 512 + (rg2 * 16 + clsbase + clsl) * 8;
    *(u32x4*)(dst + du) = *(const u32x4*)(Os + unit * 8);
  }
}

// ---------------------------------------------------------------------------
// Kernel 3: per (64-row tile rt, bh): P = Q K^T (Q pre-scaled), chord LUT
// epilogue. grid 512 x 512 thr (8 waves); wave = 16r x 256c, acc[16]
// (R2-proven no-spill shape). launch_bounds(512,4): 128-reg budget,
// 2 blocks/CU, SINGLE co-resident generation. XCD-chunked blockIdx.
// tmax per-wave (extra col-block-0 MFMA) + shfl; tid<64 fac (ILP-4).
__global__ __launch_bounds__(512, 4) void k_attn(
    const unsigned short* __restrict__ qb, const unsigned short* __restrict__ kb,
    const float2* __restrict__ lutg,
    const float* __restrict__ iw1, const float* __restrict__ ib1,
    const float* __restrict__ iw2, const float* __restrict__ ib2p,
    float* __restrict__ out) {
  __shared__ float2 Lut[LUT_N];   // 16 KB
  __shared__ float s_part[2][64];
  __shared__ float s_fac[64];

  int tid = threadIdx.x;
  int lane = tid & 63, w = tid >> 6;   // 8 waves
  int i = blockIdx.x;
  int xcd = i & 7, j2 = i >> 3;        // j2 in [0,64)
  int bh = xcd * 8 + (j2 >> 3);
  int rt = j2 & 7;                     // 64-row tile
  int rs = w & 3, ch = w >> 2;         // 4 row-stripes x 2 col-strips(256)
  int rgrp = lane >> 4, cl = lane & 15;

  // stage LUT: 16 KB via gload16 (8 waves x 2 chunks of 1KB); published by
  // the barrier AFTER the MFMA phase (loads land under compute).
#pragma unroll
  for (int c = 0; c < 2; c++) {
    int chunk = w * 2 + c;
    gload16((const char*)lutg + chunk * 1024 + lane * 16, (char*)Lut + chunk * 1024);
  }

  // Q A-fragments for this wave's 16 rows (1KB coalesced each)
  int rb = rt * 4 + rs;
  const char* Qb = (const char*)qb + (size_t)((bh * 32 + rb) * 2) * 1024;
  bf16x8 aF0 = *(const bf16x8*)(Qb + lane * 16);
  bf16x8 aF1 = *(const bf16x8*)(Qb + 1024 + lane * 16);

  const char* Kbase = (const char*)kb + (size_t)(bh * 32) * 2048;
  f32x4 zero = {0.f, 0.f, 0.f, 0.f};

  // col-block 0 (for tmax), every wave; p0 transient
  float tm1[4];
  {
    bf16x8 b0 = *(const bf16x8*)(Kbase + lane * 16);
    bf16x8 b1 = *(const bf16x8*)(Kbase + 1024 + lane * 16);
    f32x4 p0 = __builtin_amdgcn_mfma_f32_16x16x32_bf16(aF0, b0, zero, 0, 0, 0);
    p0 = __builtin_amdgcn_mfma_f32_16x16x32_bf16(aF1, b1, p0, 0, 0, 0);
    int src = lane & 48;  // cl==0 lane of this 16-group
#pragma unroll
    for (int j = 0; j < 4; j++) tm1[j] = __shfl(p0[j], src) - 1.0f;
  }

  f32x4 acc[16];
#pragma unroll
  for (int f = 0; f < 16; f++) {
    const char* Kb = Kbase + (size_t)(ch * 16 + f) * 2048;
    bf16x8 b0 = *(const bf16x8*)(Kb + lane * 16);
    bf16x8 b1 = *(const bf16x8*)(Kb + 1024 + lane * 16);
    acc[f] = __builtin_amdgcn_mfma_f32_16x16x32_bf16(aF0, b0, zero, 0, 0, 0);
    acc[f] = __builtin_amdgcn_mfma_f32_16x16x32_bf16(aF1, b1, acc[f], 0, 0, 0);
  }

  __syncthreads();  // LUT visible (gloads landed during MFMA phase)

  // u0 = p*INVW + cj[j]; u0>0 <=> tp>-20; u = clamp(u0, 0, N); xu = a'*u+b'
  const float C0 = -LUT_LO * LUT_INVW;
  float cj[4];
#pragma unroll
  for (int j = 0; j < 4; j++) cj[j] = fmaf(-tm1[j], LUT_INVW, C0);

  float rowsum[4] = {0.f, 0.f, 0.f, 0.f};
#pragma unroll
  for (int f = 0; f < 16; f++) {
#pragma unroll
    for (int j = 0; j < 4; j++) {
      float u0 = fmaf(acc[f][j], LUT_INVW, cj[j]);
      float u = fminf(fmaxf(u0, 0.0f), (float)LUT_N);    // v_med3, [0, 2048]
      int bi = (int)u;
      bi = min(bi, LUT_N - 1);
      float2 ab = Lut[bi];
      float xu = fmaf(ab.x, u, ab.y);
      xu = (u0 > 0.0f) ? xu : 0.0f;
      acc[f][j] = xu;
      rowsum[j] += xu;
    }
  }

  // row partial sums across the 16 cl lanes
#pragma unroll
  for (int j = 0; j < 4; j++) {
    float s = rowsum[j];
    s += __shfl_xor(s, 1);
    s += __shfl_xor(s, 2);
    s += __shfl_xor(s, 4);
    s += __shfl_xor(s, 8);
    if (cl == 0) s_part[ch][rs * 16 + rgrp * 4 + j] = s;
  }
  __syncthreads();

  if (tid < 64) {
    float part = s_part[0][tid] + s_part[1][tid];
    float b2 = ib2p[0];
    float fac = invmlp4(part, iw1, ib1, iw2, b2);
    float pp2 = part * fac;
    if (pp2 > 1.5f) fac *= invmlp4(pp2, iw1, ib1, iw2, b2);
    s_fac[tid] = fac;
  }
  __syncthreads();

  float* outb = out + ((size_t)bh * 512 + rt * 64) * 512;
#pragma unroll
  for (int j = 0; j < 4; j++) {
    int lrow = rs * 16 + rgrp * 4 + j;
    float fac = s_fac[lrow];
#pragma unroll
    for (int f = 0; f < 16; f++)
      __builtin_nontemporal_store(acc[f][j] * fac,
          &outb[(size_t)lrow * 512 + ch * 256 + 16 * f + cl]);
  }
}

extern "C" void kernel_launch(void* const* d_in, const int* in_sizes, int n_in,
                              void* d_out, int out_size, void* d_ws, size_t ws_size,
                              hipStream_t stream) {
  (void)in_sizes; (void)n_in; (void)out_size; (void)ws_size;
  const float* sx  = (const float*)d_in[0];
  const float* wq  = (const float*)d_in[1];
  const float* wk  = (const float*)d_in[2];
  const float* bq  = (const float*)d_in[3];
  const float* bk  = (const float*)d_in[4];
  const float* ew1 = (const float*)d_in[5];
  const float* eb1 = (const float*)d_in[6];
  const float* ew2 = (const float*)d_in[7];
  const float* eb2 = (const float*)d_in[8];
  const float* iw1 = (const float*)d_in[9];
  const float* ib1 = (const float*)d_in[10];
  const float* iw2 = (const float*)d_in[11];
  const float* ib2 = (const float*)d_in[12];
  unsigned short* wsu = (unsigned short*)d_ws;
  float2* lut = (float2*)(wsu + LUT_OFF);
  float* out = (float*)d_out;

  k_pre<<<2568, 256, 0, stream>>>(sx, wq, wk, ew1, eb1, ew2, eb2,
                                  wsu + XS_OFF, wsu + WQ_OFF, wsu + WK_OFF, lut);
  k_proj<<<dim3(64, 4, 2), 256, 0, stream>>>(wsu + XS_OFF, wsu + WQ_OFF, bq, bk, wsu + QB_OFF);
  k_attn<<<512, 512, 0, stream>>>(wsu + QB_OFF, wsu + KB_OFF, lut,
                                  iw1, ib1, iw2, ib2, out);
}

// Round 15
// 54.039 us; speedup vs baseline: 1.6265x; 1.6265x over previous
//
#include <hip/hip_runtime.h>

// Shapes (fixed): T=8, S=512, B=8, D=512, H=8, hd=64, BH=64, NE=32, NI=64.
// out: (64, 512, 512) f32.
//
// Math reduction: sum_p telescopes to (sum_t Q_t)(sum_t K_t)^T * scale, so
//   p = (Xsum@Wq^T + 8 bq)(Xsum@Wk^T + 8 bk)^T / 64   (per bh batch, hd=64)
// The 1/64 is folded into Q at projection time.
//
// Q/K are stored in MFMA-FRAGMENT ORDER: [bh][blk16][half][lane][16B], so
// k_attn operand loads are fully-coalesced 1KB dwordx4 reads. The SAME
// layout serves both A- and B-operands (identical lane->(row,k) mapping).
//
// k_attn computes P^T tiles: mfma(A=K_block, B=Q) -> D[col=q=lane&15,
// row=k=(lane>>4)*4+j]. Each lane holds 4 CONSECUTIVE k for one q-row:
//   - f32x4 nt stores (8 dwordx4/thread, was 32 dword)
//   - tm1/cj/rowsum scalars; rowsum reduce = 2 shfl (was 16)
//   - fac computed n-distributed per wave, lane-local for its row:
//     no s_fac, no 2nd barrier, no serial tail.
//
// exp-MLP epilogue: 2048-bucket chord LUT in INDEX SPACE (a',b', 16KB LDS):
// xu = a'*u + b', u = clamp(p*INVW + cj, 0, N); exact PWL off knot buckets.
//
// REGISTER RULE (R4/R6/R8/R14): VGPR+AGPR one budget (128 at 4 blk/CU).
// This kernel supports acc[8] ONLY; acc[16]+extras spilled twice (R6,R14).

#define T_  8
#define NE_ 32
#define NI_ 64

#define LUT_N   2048
#define LUT_LO  -20.0f
#define LUT_HI  3.0f
#define LUT_INVW (LUT_N / (LUT_HI - LUT_LO))     // 2048/23
#define LUT_W    ((LUT_HI - LUT_LO) / LUT_N)

typedef __attribute__((ext_vector_type(8))) short bf16x8;
typedef __attribute__((ext_vector_type(4))) float f32x4;
typedef __attribute__((ext_vector_type(4))) unsigned int u32x4;

// workspace layout, in ushort elements
#define XS_OFF 0u        // Xsum bf16 (4096 x 512)
#define WQ_OFF 2097152u  // Wq bf16 (512 x 512)
#define WK_OFF 2359296u  // Wk bf16
#define QB_OFF 2621440u  // Q bf16 frag-order (64*32*2*1024B), pre-scaled 1/64
#define KB_OFF 4718592u  // K bf16 frag-order
#define LUT_OFF 6815744u // float2 lut[2048] = 16 KB (index-space chord a',b')

__device__ inline unsigned short f2bf(float f) {
  union { float f; unsigned u; } v; v.f = f;
  unsigned r = v.u + 0x7FFFu + ((v.u >> 16) & 1u);
  return (unsigned short)(r >> 16);
}

__device__ inline void gload16(const void* g, void* l) {
  __builtin_amdgcn_global_load_lds(
      (const __attribute__((address_space(1))) void*)g,
      (__attribute__((address_space(3))) void*)l, 16, 0, 0);
}

// XOR-swizzled LDS read (k_proj GEMM tiles): 128B rows, slot ^ (row&7)
__device__ inline bf16x8 lds_read_swz(const unsigned short* base, int row, int byteoff) {
  int addr = row * 128 + (byteoff ^ ((row & 7) << 4));
  return *(const bf16x8*)((const char*)base + addr);
}

__device__ inline float expmlp_exact(float t, const float* __restrict__ w1,
                                     const float* __restrict__ b1,
                                     const float* __restrict__ w2, float b2) {
  float a = b2;
#pragma unroll
  for (int n = 0; n < NE_; n++) a += w2[n] * fmaxf(t * w1[n] + b1[n], 0.0f);
  return a;
}

// ---------------------------------------------------------------------------
// Kernel 1: Xsum = sum_t sx[t] (f32->bf16, nt loads), Wq/Wk casts, chord LUT.
__global__ __launch_bounds__(256) void k_pre(
    const float* __restrict__ sx, const float* __restrict__ wq,
    const float* __restrict__ wk, const float* __restrict__ ew1,
    const float* __restrict__ eb1, const float* __restrict__ ew2,
    const float* __restrict__ eb2p,
    unsigned short* __restrict__ xs, unsigned short* __restrict__ wqb,
    unsigned short* __restrict__ wkb, float2* __restrict__ lut) {
  int bx = blockIdx.x, tid = threadIdx.x;
  if (bx < 2048) {
    size_t i = ((size_t)bx * 256 + tid) * 4;
    f32x4 a = __builtin_nontemporal_load((const f32x4*)(sx + i));
#pragma unroll
    for (int t = 1; t < T_; t++) {
      f32x4 v = __builtin_nontemporal_load((const f32x4*)(sx + (size_t)t * 2097152 + i));
      a += v;
    }
    ushort4 o; o.x = f2bf(a[0]); o.y = f2bf(a[1]); o.z = f2bf(a[2]); o.w = f2bf(a[3]);
    *(ushort4*)(xs + i) = o;
  } else if (bx < 2560) {
    const float* src = (bx < 2304) ? wq : wk;
    unsigned short* dst = (bx < 2304) ? wqb : wkb;
    int base = (bx < 2304) ? 2048 : 2304;
    size_t i = ((size_t)(bx - base) * 256 + tid) * 4;
    float4 a = *(const float4*)(src + i);
    ushort4 o; o.x = f2bf(a.x); o.y = f2bf(a.y); o.z = f2bf(a.z); o.w = f2bf(a.w);
    *(ushort4*)(dst + i) = o;
  } else {
    // index-space chord LUT: xu(u) = a'*u + b' on bucket i (u in [i, i+1]);
    // a' = f(t_{i+1})-f(t_i), b' = f(t_i) - a'*i. Edges shared -> continuity.
    int i = (bx - 2560) * 256 + tid;
    if (i < LUT_N) {
      float b2 = eb2p[0];
      float tl = fmaf((float)i, LUT_W, LUT_LO);
      float th = fmaf((float)(i + 1), LUT_W, LUT_LO);
      float el = expmlp_exact(tl, ew1, eb1, ew2, b2);
      float eh = expmlp_exact(th, ew1, eb1, ew2, b2);
      float ap = eh - el;
      float bp = fmaf(-ap, (float)i, el);
      lut[i] = make_float2(ap, bp);
    }
  }
}

// ---------------------------------------------------------------------------
// Kernel 2: Y = Xsum(4096x512) @ W^T + 8*bias -> bf16 frag-order layout.
// z=0 (Q) additionally scaled by 1/64.  grid (64,4,2) = 512 blocks
// (2 blocks/CU), 256 thr, 64x128 tile: 4 waves of 32x64. LDS 24KB.
// Output restaged via LDS (reuses Bs) -> coalesced 16B stores.
__global__ __launch_bounds__(256, 2) void k_proj(
    const unsigned short* __restrict__ xs, const unsigned short* __restrict__ wb,
    const float* __restrict__ bq, const float* __restrict__ bk,
    unsigned short* __restrict__ outb) {
  __shared__ unsigned short As[64 * 64];    // 8 KB
  __shared__ unsigned short Bs[128 * 64];   // 16 KB (reused as Os)
  int tid = threadIdx.x;
  int lane = tid & 63, w = tid >> 6;
  int r0 = blockIdx.x * 64;
  int c0 = blockIdx.y * 128;
  int z = blockIdx.z;
  const unsigned short* W = wb + (size_t)z * 262144;
  const float* bias = z ? bk : bq;
  unsigned short* dst = outb + (size_t)z * 2097152;
  float sc = z ? 1.0f : (1.0f / 64.0f);

  int rgrp = lane >> 4, cl = lane & 15;
  int r0w = (w >> 1) * 32, c0w = (w & 1) * 64;

  f32x4 acc[2][4];
  f32x4 zero = {0.f, 0.f, 0.f, 0.f};
#pragma unroll
  for (int m = 0; m < 2; m++)
#pragma unroll
    for (int n = 0; n < 4; n++) acc[m][n] = zero;

  int rl = lane >> 3, slot = lane & 7;

  for (int kt = 0; kt < 8; kt++) {
    int k0 = kt * 64;
#pragma unroll
    for (int i = 0; i < 2; i++) {
      int chunk = w * 2 + i;
      int r = chunk * 8 + rl;
      int sw = (slot ^ (r & 7)) * 8;
      gload16(xs + (size_t)(r0 + r) * 512 + k0 + sw, (char*)As + chunk * 1024);
    }
#pragma unroll
    for (int i = 0; i < 4; i++) {
      int chunk = w * 4 + i;
      int r = chunk * 8 + rl;
      int sw = (slot ^ (r & 7)) * 8;
      gload16(W + (size_t)(c0 + r) * 512 + k0 + sw, (char*)Bs + chunk * 1024);
    }
    __syncthreads();
#pragma unroll
    for (int kb = 0; kb < 2; kb++) {
      bf16x8 af[2], bfr[4];
#pragma unroll
      for (int m = 0; m < 2; m++) af[m] = lds_read_swz(As, r0w + 16 * m + cl, kb * 64 + rgrp * 16);
#pragma unroll
      for (int n = 0; n < 4; n++) bfr[n] = lds_read_swz(Bs, c0w + 16 * n + cl, kb * 64 + rgrp * 16);
#pragma unroll
      for (int m = 0; m < 2; m++)
#pragma unroll
        for (int n = 0; n < 4; n++)
          acc[m][n] = __builtin_amdgcn_mfma_f32_16x16x32_bf16(af[m], bfr[n], acc[m][n], 0, 0, 0);
    }
    __syncthreads();
  }

  // stage: +8*bias, scale, cast -> Os (=Bs) in frag-order
  unsigned short* Os = Bs;
#pragma unroll
  for (int n = 0; n < 4; n++) {
    int cgl = c0w + 16 * n + cl;               // [0,128)
    float bv = 8.0f * bias[c0 + cgl];
    int hl = cgl >> 6, dh = cgl & 63;
    int hh = dh >> 5, rg2 = (dh >> 3) & 3, jj = dh & 7;
#pragma unroll
    for (int m = 0; m < 2; m++) {
#pragma unroll
      for (int j = 0; j < 4; j++) {
        int rgl = r0w + 16 * m + rgrp * 4 + j;  // [0,64)
        int b = rgl & 7, clsl = rgl >> 3;       // [0,8)
        Os[((((b * 2 + hl) * 2 + hh) * 4 + rg2) * 8 + clsl) * 8 + jj] =
            f2bf((acc[m][n][j] + bv) * sc);
      }
    }
  }
  __syncthreads();

  // coalesced store: 1024 x 16B units
  int cb = blockIdx.x >> 1;
  int clsbase = (blockIdx.x & 1) * 8;
  int h0 = c0 >> 6;
#pragma unroll
  for (int i2 = 0; i2 < 4; i2++) {
    int unit = i2 * 256 + tid;                  // [b:3][hl:1][hh:1][rg2:2][clsl:3]
    int clsl = unit & 7, rg2 = (unit >> 3) & 3, hh = (unit >> 5) & 1;
    int hl = (unit >> 6) & 1, b = unit >> 7;
    int bh = b * 8 + h0 + hl;
    size_t du = ((size_t)((bh * 32 + cb) * 2 + hh)) * 512 + (rg2 * 16 + clsbase + clsl) * 8;
    *(u32x4*)(dst + du) = *(const u32x4*)(Os + unit * 8);
  }
}

// ---------------------------------------------------------------------------
// Kernel 3: per (16-row q-block rb, bh): P^T tiles via mfma(K, Q), chord LUT
// epilogue, f32x4 stores. grid 2048 x 256 thr (4 waves); wave w = 128 k-col
// strip, acc[8]. launch_bounds(256,4): proven no-spill. XCD-chunked blockIdx.
__global__ __launch_bounds__(256, 4) void k_attn(
    const unsigned short* __restrict__ qb, const unsigned short* __restrict__ kb,
    const float2* __restrict__ lutg,
    const float* __restrict__ iw1, const float* __restrict__ ib1,
    const float* __restrict__ iw2, const float* __restrict__ ib2p,
    float* __restrict__ out) {
  __shared__ float2 Lut[LUT_N];   // 16 KB
  __shared__ float s_part[4][16];

  int tid = threadIdx.x;
  int lane = tid & 63, w = tid >> 6;   // w = 128-k-col strip
  int i = blockIdx.x;
  int xcd = i & 7, j2 = i >> 3;        // j2 in [0,256)
  int bh = xcd * 8 + (j2 >> 5);
  int rb = j2 & 31;                    // 16-row q-block
  int rgrp = lane >> 4, cl = lane & 15;

  // stage LUT: 16 KB via gload16 (4 waves x 4 chunks of 1KB); published by
  // the barrier AFTER the MFMA phase (loads land under compute).
#pragma unroll
  for (int c = 0; c < 4; c++) {
    int chunk = w * 4 + c;
    gload16((const char*)lutg + chunk * 1024 + lane * 16, (char*)Lut + chunk * 1024);
  }

  // Q fragments (B-operand) for this block's 16 q-rows (1KB coalesced each)
  const char* Qb = (const char*)qb + (size_t)((bh * 32 + rb) * 2) * 1024;
  bf16x8 qF0 = *(const bf16x8*)(Qb + lane * 16);
  bf16x8 qF1 = *(const bf16x8*)(Qb + 1024 + lane * 16);

  const char* Kbase = (const char*)kb + (size_t)(bh * 32) * 2048;
  f32x4 zero = {0.f, 0.f, 0.f, 0.f};

  // tmax from k-block 0: D[col=q=cl, row=k=rgrp*4+j]; P[0][q] lives in
  // lane q (rgrp 0), reg 0 -> scalar broadcast per lane's own row.
  float tm1;
  {
    bf16x8 k0 = *(const bf16x8*)(Kbase + lane * 16);
    bf16x8 k1 = *(const bf16x8*)(Kbase + 1024 + lane * 16);
    f32x4 p0 = __builtin_amdgcn_mfma_f32_16x16x32_bf16(k0, qF0, zero, 0, 0, 0);
    p0 = __builtin_amdgcn_mfma_f32_16x16x32_bf16(k1, qF1, p0, 0, 0, 0);
    tm1 = __shfl(p0[0], cl) - 1.0f;
  }

  f32x4 acc[8];
#pragma unroll
  for (int f = 0; f < 8; f++) {
    const char* Kb = Kbase + (size_t)(w * 8 + f) * 2048;
    bf16x8 k0 = *(const bf16x8*)(Kb + lane * 16);
    bf16x8 k1 = *(const bf16x8*)(Kb + 1024 + lane * 16);
    acc[f] = __builtin_amdgcn_mfma_f32_16x16x32_bf16(k0, qF0, zero, 0, 0, 0);
    acc[f] = __builtin_amdgcn_mfma_f32_16x16x32_bf16(k1, qF1, acc[f], 0, 0, 0);
  }

  __syncthreads();  // LUT visible (gloads landed during MFMA phase)

  // u0 = p*INVW + cj; u0>0 <=> tp>-20; u = clamp(u0,0,N); xu = a'*u + b'
  const float C0 = -LUT_LO * LUT_INVW;
  float cj = fmaf(-tm1, LUT_INVW, C0);

  float rowsum = 0.0f;
#pragma unroll
  for (int f = 0; f < 8; f++) {
#pragma unroll
    for (int j = 0; j < 4; j++) {
      float u0 = fmaf(acc[f][j], LUT_INVW, cj);
      float u = fminf(fmaxf(u0, 0.0f), (float)LUT_N);    // v_med3, [0, 2048]
      int bi = (int)u;
      bi = min(bi, LUT_N - 1);
      float2 ab = Lut[bi];
      float xu = fmaf(ab.x, u, ab.y);
      xu = (u0 > 0.0f) ? xu : 0.0f;
      acc[f][j] = xu;
      rowsum += xu;
    }
  }

  // row partial sums: lanes {cl, cl+16, cl+32, cl+48} share q-row cl
  rowsum += __shfl_xor(rowsum, 16);
  rowsum += __shfl_xor(rowsum, 32);
  if (lane < 16) s_part[w][lane] = rowsum;
  __syncthreads();

  float part = s_part[0][cl] + s_part[1][cl] + s_part[2][cl] + s_part[3][cl];

  // n-distributed inv-MLP: lane covers 16 n-terms (chunk = rgrp) of row cl;
  // reduce across the 4 chunks via shfl_xor(16/32). Lane-local fac, no LDS.
  float b2 = ib2p[0];
  float a = 0.0f;
#pragma unroll
  for (int nn = 0; nn < 16; nn++) {
    int n = rgrp * 16 + nn;
    a += iw2[n] * fmaxf(part * iw1[n] + ib1[n], 0.0f);
  }
  a += __shfl_xor(a, 16);
  a += __shfl_xor(a, 32);
  float pinv = a + b2;
  float pp2 = part * pinv;
  float b = 0.0f;
#pragma unroll
  for (int nn = 0; nn < 16; nn++) {
    int n = rgrp * 16 + nn;
    b += iw2[n] * fmaxf(pp2 * iw1[n] + ib1[n], 0.0f);
  }
  b += __shfl_xor(b, 16);
  b += __shfl_xor(b, 32);
  float pinv2 = b + b2;
  float fac = (pp2 > 1.5f) ? pinv * pinv2 : pinv;

  // f32x4 nt stores: row = q = cl, cols w*128 + f*16 + rgrp*4 + j
  float* outb = out + ((size_t)(bh * 512 + rb * 16 + cl)) * 512 + w * 128 + rgrp * 4;
#pragma unroll
  for (int f = 0; f < 8; f++) {
    f32x4 v;
#pragma unroll
    for (int j = 0; j < 4; j++) v[j] = acc[f][j] * fac;
    __builtin_nontemporal_store(v, (f32x4*)(outb + f * 16));
  }
}

extern "C" void kernel_launch(void* const* d_in, const int* in_sizes, int n_in,
                              void* d_out, int out_size, void* d_ws, size_t ws_size,
                              hipStream_t stream) {
  (void)in_sizes; (void)n_in; (void)out_size; (void)ws_size;
  const float* sx  = (const float*)d_in[0];
  const float* wq  = (const float*)d_in[1];
  const float* wk  = (const float*)d_in[2];
  const float* bq  = (const float*)d_in[3];
  const float* bk  = (const float*)d_in[4];
  const float* ew1 = (const float*)d_in[5];
  const float* eb1 = (const float*)d_in[6];
  const float* ew2 = (const float*)d_in[7];
  const float* eb2 = (const float*)d_in[8];
  const float* iw1 = (const float*)d_in[9];
  const float* ib1 = (const float*)d_in[10];
  const float* iw2 = (const float*)d_in[11];
  const float* ib2 = (const float*)d_in[12];
  unsigned short* wsu = (unsigned short*)d_ws;
  float2* lut = (float2*)(wsu + LUT_OFF);
  float* out = (float*)d_out;

  k_pre<<<2568, 256, 0, stream>>>(sx, wq, wk, ew1, eb1, ew2, eb2,
                                  wsu + XS_OFF, wsu + WQ_OFF, wsu + WK_OFF, lut);
  k_proj<<<dim3(64, 4, 2), 256, 0, stream>>>(wsu + XS_OFF, wsu + WQ_OFF, bq, bk, wsu + QB_OFF);
  k_attn<<<2048, 256, 0, stream>>>(wsu + QB_OFF, wsu + KB_OFF, lut,
                                   iw1, ib1, iw2, ib2, out);
}